// Round 9
// baseline (150.955 us; speedup 1.0000x reference)
//
#include <hip/hip_runtime.h>
#include <math.h>

#define NQ 6
#define NL 3

// ---------- compile-time CNOT-ring permutation (bench-validated rounds 2-7) ----------
constexpr int cnot_map(int k, int ctrl, int tgt) {
    const int cb = 1 << (5 - ctrl), tb = 1 << (5 - tgt);
    return (k & cb) ? (k ^ tb) : k;
}
constexpr int ring_map(int k) {
    k = cnot_map(k, 5, 0);
    k = cnot_map(k, 4, 5);
    k = cnot_map(k, 3, 4);
    k = cnot_map(k, 2, 3);
    k = cnot_map(k, 1, 2);
    k = cnot_map(k, 0, 1);
    return k;
}

// 4-lane split: lane sub-id u = (B5<<1)|B4; local slot j = k & 15 (bits B3..B0).
// Gather algebra (derived + verified): m5=B5^B0, m4=B4^B5^B0, m3=B3^B4,
// m2=B2^B3, m1=B1^B2, m0=B0^B1. Hence:
//   src_lane = u ^ delta, delta = (B0<<1) | (B5^B0)      [B0 = j&1, B5 = u1]
//   src_slot = base_slot(j) ^ (DEST_u0 << 3)             [dest's own u0!]
constexpr int base_slot(int j) {
    const int b3 = (j >> 3) & 1, b2 = (j >> 2) & 1, b1 = (j >> 1) & 1, b0 = j & 1;
    return (b3 << 3) | ((b2 ^ b3) << 2) | ((b1 ^ b2) << 1) | (b0 ^ b1);
}
constexpr bool check_ring() {
    for (int k = 0; k < 64; k++) {
        const int m = ring_map(k);
        const int u = k >> 4, j = k & 15;
        const int b5 = (k >> 5) & 1, b4 = (k >> 4) & 1, b0 = k & 1;
        const int delta = (b0 << 1) | (b5 ^ b0);
        if ((m >> 4) != (u ^ delta)) return false;
        if ((m & 15) != (base_slot(j) ^ (b4 << 3))) return false;  // dest u0
    }
    return true;
}
static_assert(check_ring(), "ring decomposition mismatch vs validated ring_map");

// ---- prep kernel: M = RZ(a2)@RY(a1)@RZ(a0), SU(2) form (m00, m01) ----
__global__ void gate_prep(const float* __restrict__ w, float4* __restrict__ M) {
    const int g = threadIdx.x;
    if (g >= NL * NQ) return;
    const float a0 = w[g * 3 + 0], a1 = w[g * 3 + 1], a2 = w[g * 3 + 2];
    const float ch = cosf(0.5f * a1), sh = sinf(0.5f * a1);
    const float cp = cosf(0.5f * (a0 + a2)), sp = sinf(0.5f * (a0 + a2));
    const float cm = cosf(0.5f * (a0 - a2)), sm = sinf(0.5f * (a0 - a2));
    M[g] = make_float4(ch * cp, -ch * sp, -sh * cm, -sh * sm);
}

__global__ __launch_bounds__(256)
void qsim_kernel(const float* __restrict__ x, const float4* __restrict__ M,
                 float* __restrict__ out, int B) {
    const int tid = blockIdx.x * blockDim.x + threadIdx.x;
    const int b = tid >> 2;
    if (b >= B) return;
    const int u = tid & 3;
    const bool u0 = (u & 1) != 0;    // = amp bit4 (qubit 1)
    const bool uhi = (u & 2) != 0;   // = amp bit5 (qubit 0)

    // ---- x[b][0..5]; all 4 lanes of a quad read the same row (cacheline hit) ----
    const float2* x2 = (const float2*)x;
    const float2 v0 = x2[b * 3 + 0];
    const float2 v1 = x2[b * 3 + 1];
    const float2 v2 = x2[b * 3 + 2];
    const float xi[NQ] = {v0.x, v0.y, v1.x, v1.y, v2.x, v2.y};

    // phi = (pi/2)*tanh(x); v_sin/v_cos take REVOLUTIONS: |t/4| <= 0.25, no range reduction
    float C[NQ], S[NQ];
#pragma unroll
    for (int i = 0; i < NQ; i++) {
        const float e = __builtin_amdgcn_exp2f(2.885390081777927f * xi[i]); // e^{2x}
        const float t = 1.0f - 2.0f * __builtin_amdgcn_rcpf(e + 1.0f);      // tanh(x)
        S[i] = __builtin_amdgcn_sinf(0.25f * t);
        C[i] = __builtin_amdgcn_cosf(0.25f * t);
    }

    float ar[16], ai[16];   // amplitudes for k = (u<<4) | j

    // G = M @ RY(c,s): g00 = m00*c + m01*s ; g01 = -m00*s + m01*c  (SU(2))
#define GCOEF(mq, c, s, g00r, g00i, g01r, g01i)                         \
    const float g00r = (mq).x * (c) + (mq).z * (s);                     \
    const float g00i = (mq).y * (c) + (mq).w * (s);                     \
    const float g01r = (mq).z * (c) - (mq).x * (s);                     \
    const float g01i = (mq).w * (c) - (mq).y * (s);

    // ---- layer 0 on |0>: product state. base = row(q0 by uhi) * row(q1 by u0) ----
    {
        const float4 m0 = M[0];
        GCOEF(m0, C[0], S[0], a00r, a00i, a01r, a01i)
        const float t0r = uhi ? -a01r : a00r;   // col0 row: g00 or -conj(g01)
        const float t0i = uhi ?  a01i : a00i;
        const float4 m1 = M[1];
        GCOEF(m1, C[1], S[1], b00r, b00i, b01r, b01i)
        const float t1r = u0 ? -b01r : b00r;
        const float t1i = u0 ?  b01i : b00i;
        ar[0] = t0r * t1r - t0i * t1i;
        ai[0] = t0r * t1i + t0i * t1r;
    }
#pragma unroll
    for (int q = 2; q < 6; q++) {
        const float4 mq = M[q];
        GCOEF(mq, C[q], S[q], g00r, g00i, g01r, g01i)
        const float Arr = g00r, Ari = g00i;      // bit=0 factor (g00)
        const float Brr = -g01r, Bri = g01i;     // bit=1 factor (-conj(g01))
        const int bbit = 1 << (5 - q);
#pragma unroll
        for (int j = 0; j < 16; j++) {
            if ((j & ((1 << (6 - q)) - 1)) == 0) {
                const float pr = ar[j], pi = ai[j];
                ar[j | bbit] = pr * Brr - pi * Bri;
                ai[j | bbit] = pr * Bri + pi * Brr;
                ar[j] = pr * Arr - pi * Ari;
                ai[j] = pr * Ari + pi * Arr;
            }
        }
    }

    // ---- ring restoration: re-canonicalize after CNOT ring ----
    // Staging key: each lane's presented value is consumed by exactly one dest
    // whose u0 = own_u0 ^ own_u1 (even j: xor1 among upper pair; odd j: xor3/xor2
    // pairing). Lanes 0,1 consume their own ver locally on even j (key = own u0 =
    // u0^uhi since uhi=0). So sel = u0 ^ uhi everywhere.
    const bool sel = (u0 != uhi);
    auto do_ring = [&]() {
        float ver[8], vei[8], vor[8], voi[8];
#pragma unroll
        for (int i = 0; i < 8; i++) {
            const int be = base_slot(2 * i);
            const int bo = base_slot(2 * i + 1);
            ver[i] = sel ? ar[be ^ 8] : ar[be];
            vei[i] = sel ? ai[be ^ 8] : ai[be];
            vor[i] = sel ? ar[bo ^ 8] : ar[bo];
            voi[i] = sel ? ai[bo ^ 8] : ai[bo];
        }
        float r1r[8], r1i[8], r2r[8], r2i[8], r3r[8], r3i[8];
#pragma unroll
        for (int i = 0; i < 8; i++) { r1r[i] = __shfl_xor(ver[i], 1, 64); r1i[i] = __shfl_xor(vei[i], 1, 64); }
#pragma unroll
        for (int i = 0; i < 8; i++) { r2r[i] = __shfl_xor(vor[i], 2, 64); r2i[i] = __shfl_xor(voi[i], 2, 64); }
#pragma unroll
        for (int i = 0; i < 8; i++) { r3r[i] = __shfl_xor(vor[i], 3, 64); r3i[i] = __shfl_xor(voi[i], 3, 64); }
        // receive: even j: u1=0 local (own ver), u1=1 from xor1; odd j: u1=0 from xor3, u1=1 from xor2
        float nr[16], ni[16];
#pragma unroll
        for (int i = 0; i < 8; i++) {
            nr[2 * i]     = uhi ? r1r[i] : ver[i];
            ni[2 * i]     = uhi ? r1i[i] : vei[i];
            nr[2 * i + 1] = uhi ? r2r[i] : r3r[i];
            ni[2 * i + 1] = uhi ? r2i[i] : r3i[i];
        }
#pragma unroll
        for (int j = 0; j < 16; j++) { ar[j] = nr[j]; ai[j] = ni[j]; }
    };

    // cross-lane gate on a lane-bit qubit: hlo = this lane holds the bit=0 row
    auto cross_gate = [&](const float4 mq, const float c, const float s,
                          const bool hlo, const int mask) {
        GCOEF(mq, c, s, g00r, g00i, g01r, g01i)
        const float alr = g00r;
        const float ali = hlo ? g00i : -g00i;
        const float gmr = hlo ? g01r : -g01r;
        const float gmi = g01i;
#pragma unroll
        for (int j = 0; j < 16; j++) {
            const float orr = ar[j], oii = ai[j];
            const float prr = __shfl_xor(orr, mask, 64);
            const float pii = __shfl_xor(oii, mask, 64);
            ar[j] = alr * orr - ali * oii + gmr * prr - gmi * pii;
            ai[j] = alr * oii + ali * orr + gmr * pii + gmi * prr;
        }
    };

    auto dense_layer = [&](const int layer) {
        asm volatile("" ::: "memory");  // keep this layer's M loads just-in-time
        cross_gate(M[layer * NQ + 0], C[0], S[0], !uhi, 2);  // q0: bit5 = u1
        cross_gate(M[layer * NQ + 1], C[1], S[1], !u0, 1);   // q1: bit4 = u0
#pragma unroll
        for (int q = 2; q < 6; q++) {                        // q2..q5 lane-local
            const float4 mq = M[layer * NQ + q];
            GCOEF(mq, C[q], S[q], g00r, g00i, g01r, g01i)
            const int bbit = 1 << (5 - q);
#pragma unroll
            for (int j = 0; j < 16; j++) {
                if (!(j & bbit)) {
                    const int t2 = j | bbit;
                    const float b0r = ar[j], b0i = ai[j];
                    const float b1r = ar[t2], b1i = ai[t2];
                    ar[j]  = g00r * b0r - g00i * b0i + g01r * b1r - g01i * b1i;
                    ai[j]  = g00r * b0i + g00i * b0r + g01r * b1i + g01i * b1r;
                    ar[t2] = -g01r * b0r - g01i * b0i + g00r * b1r + g00i * b1i;
                    ai[t2] = -g01r * b0i + g01i * b0r + g00r * b1i - g00i * b1r;
                }
            }
        }
    };

    do_ring();
    dense_layer(1);
    do_ring();
    dense_layer(2);
    do_ring();

    // ---- expvals: per-lane partials, quad all-reduce ----
    float P = 0.f, T2 = 0.f, T3 = 0.f, T4 = 0.f, T5 = 0.f;
#pragma unroll
    for (int j = 0; j < 16; j++) {
        const float p = ar[j] * ar[j] + ai[j] * ai[j];
        P += p;
        if (j & 8) T2 += p;
        if (j & 4) T3 += p;
        if (j & 2) T4 += p;
        if (j & 1) T5 += p;
    }
    auto qsum = [](float v) {
        v += __shfl_xor(v, 1, 64);
        v += __shfl_xor(v, 2, 64);
        return v;
    };
    const float Ptot = qsum(P);
    const float acc0 = qsum(uhi ? -P : P);   // qubit0 sign = b5 = u1
    const float acc1 = qsum(u0 ? -P : P);    // qubit1 sign = b4 = u0
    const float acc2 = Ptot - 2.f * qsum(T2);
    const float acc3 = Ptot - 2.f * qsum(T3);
    const float acc4 = Ptot - 2.f * qsum(T4);
    const float acc5 = Ptot - 2.f * qsum(T5);

    // lanes u=0,1,2 write one float2 each: out[b][0..5]
    const float2 wv = (u == 0) ? make_float2(acc0, acc1)
                    : (u == 1) ? make_float2(acc2, acc3)
                               : make_float2(acc4, acc5);
    if (u < 3) ((float2*)out)[b * 3 + u] = wv;
#undef GCOEF
}

extern "C" void kernel_launch(void* const* d_in, const int* in_sizes, int n_in,
                              void* d_out, int out_size, void* d_ws, size_t ws_size,
                              hipStream_t stream) {
    const float* x = (const float*)d_in[0];
    const float* w = (const float*)d_in[1];
    float* out = (float*)d_out;
    float4* M = (float4*)d_ws;  // 18 * 16 B
    const int B = in_sizes[0] / NQ;
    gate_prep<<<1, 64, 0, stream>>>(w, M);
    const long long threads = 4LL * B;
    const int block = 256;
    const int grid = (int)((threads + block - 1) / block);
    qsim_kernel<<<grid, block, 0, stream>>>(x, M, out, B);
}

// Round 10
// 144.381 us; speedup vs baseline: 1.0455x; 1.0455x over previous
//
#include <hip/hip_runtime.h>
#include <math.h>

#define NQ 6
#define NL 3

// ---------- compile-time CNOT-ring permutation (bench-validated rounds 2-9) ----------
constexpr int cnot_map(int k, int ctrl, int tgt) {
    const int cb = 1 << (5 - ctrl), tb = 1 << (5 - tgt);
    return (k & cb) ? (k ^ tb) : k;
}
constexpr int ring_map(int k) {
    k = cnot_map(k, 5, 0);
    k = cnot_map(k, 4, 5);
    k = cnot_map(k, 3, 4);
    k = cnot_map(k, 2, 3);
    k = cnot_map(k, 1, 2);
    k = cnot_map(k, 0, 1);
    return k;
}

// 2-lane split: lane parity h = amp bit5; slot j = k & 31.
// Ring closed form: src = ((h^b0)<<5) | (G(j) ^ (h<<4)):
constexpr int Gmap(int j) {
    const int b4 = (j >> 4) & 1, b3 = (j >> 3) & 1, b2 = (j >> 2) & 1,
              b1 = (j >> 1) & 1, b0 = j & 1;
    return ((b4 ^ b0) << 4) | ((b3 ^ b4) << 3) | ((b2 ^ b3) << 2) |
           ((b1 ^ b2) << 1) | (b0 ^ b1);
}
constexpr bool check_ring() {
    for (int k = 0; k < 64; k++) {
        const int h = k >> 5, j = k & 31, b0 = k & 1;
        if (ring_map(k) != (((h ^ b0) << 5) | (Gmap(j) ^ (h << 4)))) return false;
    }
    return true;
}
static_assert(check_ring(), "lean-ring decomposition mismatch vs validated ring_map");

// Final-ring fold: measuring bit (5-q) of post-ring index k == parity(mask_q & p)
// on pre-ring index p = ring_map(k). mask_q = row (5-q) of R^{-1}.
constexpr int SIGN_MASK[6] = {0x1F, 0x30, 0x38, 0x3C, 0x3E, 0x3F};
constexpr bool check_signs() {
    for (int q = 0; q < 6; q++)
        for (int k = 0; k < 64; k++) {
            const int par = __builtin_popcount(SIGN_MASK[q] & ring_map(k)) & 1;
            if (par != ((k >> (5 - q)) & 1)) return false;
        }
    return true;
}
static_assert(check_signs(), "expval sign-fold mismatch vs validated ring_map");

// ---- prep kernel: M = RZ(a2)@RY(a1)@RZ(a0), SU(2) form (m00, m01) ----
__global__ void gate_prep(const float* __restrict__ w, float4* __restrict__ M) {
    const int g = threadIdx.x;
    if (g >= NL * NQ) return;
    const float a0 = w[g * 3 + 0], a1 = w[g * 3 + 1], a2 = w[g * 3 + 2];
    const float ch = cosf(0.5f * a1), sh = sinf(0.5f * a1);
    const float cp = cosf(0.5f * (a0 + a2)), sp = sinf(0.5f * (a0 + a2));
    const float cm = cosf(0.5f * (a0 - a2)), sm = sinf(0.5f * (a0 - a2));
    M[g] = make_float4(ch * cp, -ch * sp, -sh * cm, -sh * sm);
}

__global__ __launch_bounds__(256)
void qsim_kernel(const float* __restrict__ x, const float4* __restrict__ M,
                 float* __restrict__ out, int B) {
    const int tid = blockIdx.x * blockDim.x + threadIdx.x;
    const int b = tid >> 1;
    if (b >= B) return;
    const bool h0 = (tid & 1) == 0;   // lane parity h: h0 <=> amp bit5 = 0

    const float2* x2 = (const float2*)x;
    const float2 v0 = x2[b * 3 + 0];
    const float2 v1 = x2[b * 3 + 1];
    const float2 v2 = x2[b * 3 + 2];
    const float xi[NQ] = {v0.x, v0.y, v1.x, v1.y, v2.x, v2.y};

    // phi = (pi/2)*tanh(x); v_sin/v_cos take REVOLUTIONS: |t/4| <= 0.25, no range reduction
    float C[NQ], S[NQ];
#pragma unroll
    for (int i = 0; i < NQ; i++) {
        const float e = __builtin_amdgcn_exp2f(2.885390081777927f * xi[i]); // e^{2x}
        const float t = 1.0f - 2.0f * __builtin_amdgcn_rcpf(e + 1.0f);      // tanh(x)
        S[i] = __builtin_amdgcn_sinf(0.25f * t);
        C[i] = __builtin_amdgcn_cosf(0.25f * t);
    }

    float ar[32], ai[32];  // amplitudes for logical k = (h<<5)|j

    // G = M @ RY(c,s): g00 = m00*c + m01*s ; g01 = -m00*s + m01*c  (SU(2))
#define GCOEF(mq, c, s, g00r, g00i, g01r, g01i)                         \
    const float g00r = (mq).x * (c) + (mq).z * (s);                     \
    const float g00i = (mq).y * (c) + (mq).w * (s);                     \
    const float g01r = (mq).z * (c) - (mq).x * (s);                     \
    const float g01i = (mq).w * (c) - (mq).y * (s);

    // ---- layer 0 on |0>: product-state cascade (bench-validated round 4) ----
    {
        const float4 m0 = M[0];
        GCOEF(m0, C[0], S[0], g00r, g00i, g01r, g01i)
        ar[0] = h0 ? g00r : -g01r;
        ai[0] = h0 ? g00i : g01i;
    }
#pragma unroll
    for (int q = 1; q < NQ; q++) {
        const float4 mq = M[q];
        GCOEF(mq, C[q], S[q], g00r, g00i, g01r, g01i)
        const float Ar = g00r, Ai = g00i;     // bit=0 factor
        const float Br = -g01r, Bi = g01i;    // bit=1 factor (-conj(g01))
        const int bbit = 1 << (5 - q);
        const int prevmask = (0x1F << (6 - q)) & 0x1F;
#pragma unroll
        for (int s2 = 0; s2 < 32; s2++) {
            if ((s2 & (~prevmask & 31)) == 0) {
                const float pr = ar[s2], pi = ai[s2];
                ar[s2 | bbit] = pr * Br - pi * Bi;
                ai[s2 | bbit] = pr * Bi + pi * Br;
                ar[s2] = pr * Ar - pi * Ai;
                ai[s2] = pr * Ai + pi * Ar;
            }
        }
    }

    // ---- lean ring: new[(h,j)] = old[((h^b0)<<5) | (G(j)^(h<<4))] ----
    auto do_ring = [&]() {
        // stage for partner (dest lane = own^1): st[i] = ar[G(2i+1) ^ ((own^1)<<4)]
        float str[16], sti[16];
#pragma unroll
        for (int i = 0; i < 16; i++) {
            const int g1 = Gmap(2 * i + 1);
            str[i] = h0 ? ar[g1 ^ 16] : ar[g1];
            sti[i] = h0 ? ai[g1 ^ 16] : ai[g1];
        }
        float rr[16], ri[16];
#pragma unroll
        for (int i = 0; i < 16; i++) {
            rr[i] = __shfl_xor(str[i], 1, 64);
            ri[i] = __shfl_xor(sti[i], 1, 64);
        }
        float nr[32], ni[32];
#pragma unroll
        for (int i = 0; i < 16; i++) {
            const int ge = Gmap(2 * i);
            nr[2 * i]     = h0 ? ar[ge] : ar[ge ^ 16];  // even j: local
            ni[2 * i]     = h0 ? ai[ge] : ai[ge ^ 16];
            nr[2 * i + 1] = rr[i];                       // odd j: cross, no select
            ni[2 * i + 1] = ri[i];
        }
#pragma unroll
        for (int j = 0; j < 32; j++) { ar[j] = nr[j]; ai[j] = ni[j]; }
    };

    do_ring();  // after layer 0

    // ---- layers 1..2: ONE code copy (I$!). Ring after layer 1 only; layer 2's
    // ring is folded into the expval sign masks below. ----
#pragma unroll 1
    for (int layer = 1; layer < 3; layer++) {
        const float4* Ml = M + layer * NQ;
        // q = 0: cross-lane gate (bit5 = lane parity) — bench-validated round 4
        {
            const float4 mq = Ml[0];
            GCOEF(mq, C[0], S[0], g00r, g00i, g01r, g01i)
            const float alr = g00r;
            const float ali = h0 ? g00i : -g00i;
            const float gmr = h0 ? g01r : -g01r;
            const float gmi = g01i;
#pragma unroll
            for (int s2 = 0; s2 < 32; s2++) {
                const float orr = ar[s2], oii = ai[s2];
                const float prr = __shfl_xor(orr, 1, 64);
                const float pii = __shfl_xor(oii, 1, 64);
                ar[s2] = alr * orr - ali * oii + gmr * prr - gmi * pii;
                ai[s2] = alr * oii + ali * orr + gmr * pii + gmi * prr;
            }
        }
        // q = 1..5: lane-local gates
#pragma unroll
        for (int q = 1; q < NQ; q++) {
            const float4 mq = Ml[q];
            GCOEF(mq, C[q], S[q], g00r, g00i, g01r, g01i)
            const int bbit = 1 << (5 - q);
#pragma unroll
            for (int s2 = 0; s2 < 32; s2++) {
                if (!(s2 & bbit)) {
                    const int t2 = s2 | bbit;
                    const float b0r = ar[s2], b0i = ai[s2];
                    const float b1r = ar[t2], b1i = ai[t2];
                    ar[s2] = g00r * b0r - g00i * b0i + g01r * b1r - g01i * b1i;
                    ai[s2] = g00r * b0i + g00i * b0r + g01r * b1i + g01i * b1r;
                    ar[t2] = -g01r * b0r - g01i * b0i + g00r * b1r + g00i * b1i;
                    ai[t2] = -g01r * b0i + g01i * b0r + g00r * b1i - g00i * b1r;
                }
            }
        }
        if (layer == 1) do_ring();
    }

    // ---- expvals with folded final ring: 5 compile-time-signed partials ----
    // slot-part masks: F0<->0x1F (shared by qubits 0 and 5), F1<->0x10,
    // F2<->0x18, F3<->0x1C, F4<->0x1E; lane bit adds h-flip to qubits 1..5.
    float F0 = 0.f, F1 = 0.f, F2 = 0.f, F3 = 0.f, F4 = 0.f;
#pragma unroll
    for (int j = 0; j < 32; j++) {
        const float p = ar[j] * ar[j] + ai[j] * ai[j];
        if (__builtin_popcount(j & 0x1F) & 1) F0 -= p; else F0 += p;
        if (__builtin_popcount(j & 0x10) & 1) F1 -= p; else F1 += p;
        if (__builtin_popcount(j & 0x18) & 1) F2 -= p; else F2 += p;
        if (__builtin_popcount(j & 0x1C) & 1) F3 -= p; else F3 += p;
        if (__builtin_popcount(j & 0x1E) & 1) F4 -= p; else F4 += p;
    }
    const float d1 = h0 ? F1 : -F1;
    const float d2 = h0 ? F2 : -F2;
    const float d3 = h0 ? F3 : -F3;
    const float d4 = h0 ? F4 : -F4;
    const float d5 = h0 ? F0 : -F0;
    float acc[NQ];
    acc[0] = F0 + __shfl_xor(F0, 1, 64);   // qubit0: mask 0x1F, no lane bit
    acc[1] = d1 + __shfl_xor(d1, 1, 64);
    acc[2] = d2 + __shfl_xor(d2, 1, 64);
    acc[3] = d3 + __shfl_xor(d3, 1, 64);
    acc[4] = d4 + __shfl_xor(d4, 1, 64);
    acc[5] = d5 + __shfl_xor(d5, 1, 64);

    const int off = b * 6 + (h0 ? 0 : 3);
    out[off + 0] = acc[h0 ? 0 : 3];
    out[off + 1] = acc[h0 ? 1 : 4];
    out[off + 2] = acc[h0 ? 2 : 5];
#undef GCOEF
}

extern "C" void kernel_launch(void* const* d_in, const int* in_sizes, int n_in,
                              void* d_out, int out_size, void* d_ws, size_t ws_size,
                              hipStream_t stream) {
    const float* x = (const float*)d_in[0];
    const float* w = (const float*)d_in[1];
    float* out = (float*)d_out;
    float4* M = (float4*)d_ws;  // 18 * 16 B
    const int B = in_sizes[0] / NQ;
    gate_prep<<<1, 64, 0, stream>>>(w, M);
    const int threads = 2 * B;
    const int block = 256;
    const int grid = (threads + block - 1) / block;
    qsim_kernel<<<grid, block, 0, stream>>>(x, M, out, B);
}

// Round 11
// 100.080 us; speedup vs baseline: 1.5083x; 1.4427x over previous
//
#include <hip/hip_runtime.h>
#include <math.h>

#define NQ 6
#define NL 3

typedef float v2f __attribute__((ext_vector_type(2)));

// ---------- compile-time CNOT-ring permutation (bench-validated rounds 2-10) ----------
constexpr int cnot_map(int k, int ctrl, int tgt) {
    const int cb = 1 << (5 - ctrl), tb = 1 << (5 - tgt);
    return (k & cb) ? (k ^ tb) : k;
}
constexpr int ring_map(int k) {
    k = cnot_map(k, 5, 0);
    k = cnot_map(k, 4, 5);
    k = cnot_map(k, 3, 4);
    k = cnot_map(k, 2, 3);
    k = cnot_map(k, 1, 2);
    k = cnot_map(k, 0, 1);
    return k;
}

// Packed layout: lane parity h = amp bit5; float2 component c = bit4;
// vector index m = bits 3..0.  Ring gather in this layout:
//   out(h,c,m) <- lane h^b0, comp c^b0^h, vector Gm0(m)^(c<<3),  b0 = m&1
constexpr int Gm0(int m) {
    const int b3 = (m >> 3) & 1, b2 = (m >> 2) & 1, b1 = (m >> 1) & 1, b0 = m & 1;
    return (b3 << 3) | ((b2 ^ b3) << 2) | ((b1 ^ b2) << 1) | (b0 ^ b1);
}
constexpr bool check_ring_packed() {
    for (int h = 0; h < 2; h++)
        for (int c = 0; c < 2; c++)
            for (int m = 0; m < 16; m++) {
                const int k = (h << 5) | (c << 4) | m, b0 = m & 1;
                const int src = ((h ^ b0) << 5) | ((c ^ b0 ^ h) << 4) | (Gm0(m) ^ (c << 3));
                if (ring_map(k) != src) return false;
            }
    return true;
}
static_assert(check_ring_packed(), "packed-ring decomposition mismatch vs validated ring_map");

// Final-ring fold into expval signs (bench-validated round 10):
constexpr int SIGN_MASK[6] = {0x1F, 0x30, 0x38, 0x3C, 0x3E, 0x3F};
constexpr bool check_signs() {
    for (int q = 0; q < 6; q++)
        for (int k = 0; k < 64; k++) {
            const int par = __builtin_popcount(SIGN_MASK[q] & ring_map(k)) & 1;
            if (par != ((k >> (5 - q)) & 1)) return false;
        }
    return true;
}
static_assert(check_signs(), "expval sign-fold mismatch vs validated ring_map");

// ---- prep kernel: M = RZ(a2)@RY(a1)@RZ(a0), SU(2) form (m00, m01) ----
__global__ void gate_prep(const float* __restrict__ w, float4* __restrict__ M) {
    const int g = threadIdx.x;
    if (g >= NL * NQ) return;
    const float a0 = w[g * 3 + 0], a1 = w[g * 3 + 1], a2 = w[g * 3 + 2];
    const float ch = cosf(0.5f * a1), sh = sinf(0.5f * a1);
    const float cp = cosf(0.5f * (a0 + a2)), sp = sinf(0.5f * (a0 + a2));
    const float cm = cosf(0.5f * (a0 - a2)), sm = sinf(0.5f * (a0 - a2));
    M[g] = make_float4(ch * cp, -ch * sp, -sh * cm, -sh * sm);
}

// G = M @ RY(c,s): g00 = m00*c + m01*s ; g01 = -m00*s + m01*c  (SU(2))
#define GCOEF(mq, c, s, g00r, g00i, g01r, g01i)                         \
    const float g00r = (mq).x * (c) + (mq).z * (s);                     \
    const float g00i = (mq).y * (c) + (mq).w * (s);                     \
    const float g01r = (mq).z * (c) - (mq).x * (s);                     \
    const float g01i = (mq).w * (c) - (mq).y * (s);

#define SHFL2(v) ((v2f){__shfl_xor((v).x, 1, 64), __shfl_xor((v).y, 1, 64)})

// Ring: selection keyed on own h (staging for partner == own even-m pattern);
// odd m crosses lanes (32 shfl/ring), even m local.
#define DO_RING() do {                                                   \
    v2f nRr[16], nRi[16];                                                \
    _Pragma("unroll")                                                    \
    for (int m = 0; m < 16; m++) {                                       \
        const int V0 = Gm0(m), V1 = V0 ^ 8;                              \
        const v2f tr = h0 ? (v2f){Rr[V0].x, Rr[V1].y}                    \
                          : (v2f){Rr[V0].y, Rr[V1].x};                   \
        const v2f ti = h0 ? (v2f){Ri[V0].x, Ri[V1].y}                    \
                          : (v2f){Ri[V0].y, Ri[V1].x};                   \
        if (m & 1) { nRr[m] = SHFL2(tr); nRi[m] = SHFL2(ti); }           \
        else       { nRr[m] = tr;        nRi[m] = ti;        }           \
    }                                                                    \
    _Pragma("unroll")                                                    \
    for (int m = 0; m < 16; m++) { Rr[m] = nRr[m]; Ri[m] = nRi[m]; }     \
} while (0)

#define DENSE_LAYER(LYR) do {                                            \
    asm volatile("" ::: "memory"); /* keep this layer's M loads JIT */   \
    { /* q0: cross-lane gate (bit5 = lane parity), round-4 algebra */    \
        const float4 mq = M[(LYR) * NQ + 0];                             \
        GCOEF(mq, C[0], S[0], g00r, g00i, g01r, g01i)                    \
        const float alr = g00r;                                          \
        const float ali = h0 ? g00i : -g00i;                             \
        const float gmr = h0 ? g01r : -g01r;                             \
        const float gmi = g01i;                                          \
        _Pragma("unroll")                                                \
        for (int m = 0; m < 16; m++) {                                   \
            const v2f R0 = Rr[m], I0 = Ri[m];                            \
            const v2f Rp = SHFL2(R0), Ip = SHFL2(I0);                    \
            Rr[m] = R0 * alr - I0 * ali + Rp * gmr - Ip * gmi;           \
            Ri[m] = I0 * alr + R0 * ali + Ip * gmr + Rp * gmi;           \
        }                                                                \
    }                                                                    \
    { /* q1: intra-vector gate (bit4 = component), round-6 algebra */    \
        const float4 mq = M[(LYR) * NQ + 1];                             \
        GCOEF(mq, C[1], S[1], g00r, g00i, g01r, g01i)                    \
        const v2f P1 = (v2f){ g00r, -g01r};                              \
        const v2f P2 = (v2f){-g00i, -g01i};                              \
        const v2f P3 = (v2f){ g01r,  g00r};                              \
        const v2f P4 = (v2f){-g01i,  g00i};                              \
        _Pragma("unroll")                                                \
        for (int m = 0; m < 16; m++) {                                   \
            const v2f Rv = Rr[m], Iv = Ri[m];                            \
            const v2f Rxx = (v2f){Rv.x, Rv.x}, Ryy = (v2f){Rv.y, Rv.y};  \
            const v2f Ixx = (v2f){Iv.x, Iv.x}, Iyy = (v2f){Iv.y, Iv.y};  \
            Rr[m] = Rxx * P1 + Ixx * P2 + Ryy * P3 + Iyy * P4;           \
            Ri[m] = Ixx * P1 - Rxx * P2 + Iyy * P3 - Ryy * P4;           \
        }                                                                \
    }                                                                    \
    /* q2..q5: vector-pair gates (bits 3..0) — pure pk, round-10 algebra */ \
    _Pragma("unroll")                                                    \
    for (int q = 2; q < 6; q++) {                                        \
        const float4 mq = M[(LYR) * NQ + q];                             \
        GCOEF(mq, C[q], S[q], g00r, g00i, g01r, g01i)                    \
        const int bit = 1 << (5 - q);                                    \
        _Pragma("unroll")                                                \
        for (int m = 0; m < 16; m++) {                                   \
            if (!(m & bit)) {                                            \
                const int wv = m | bit;                                  \
                const v2f R0 = Rr[m], I0 = Ri[m];                        \
                const v2f R1 = Rr[wv], I1 = Ri[wv];                      \
                Rr[m]  = R0 * g00r - I0 * g00i + R1 * g01r - I1 * g01i;  \
                Ri[m]  = I0 * g00r + R0 * g00i + I1 * g01r + R1 * g01i;  \
                Rr[wv] = R1 * g00r + I1 * g00i - R0 * g01r - I0 * g01i;  \
                Ri[wv] = I1 * g00r - R1 * g00i - I0 * g01r + R0 * g01i;  \
            }                                                            \
        }                                                                \
    }                                                                    \
} while (0)

__global__ __launch_bounds__(256)
void qsim_kernel(const float* __restrict__ x, const float4* __restrict__ M,
                 float* __restrict__ out, int B) {
    const int tid = blockIdx.x * blockDim.x + threadIdx.x;
    const int b = tid >> 1;
    if (b >= B) return;
    const bool h0 = (tid & 1) == 0;   // lane parity h: h0 <=> amp bit5 = 0

    const float2* x2 = (const float2*)x;
    const float2 v0 = x2[b * 3 + 0];
    const float2 v1 = x2[b * 3 + 1];
    const float2 v2 = x2[b * 3 + 2];
    const float xi[NQ] = {v0.x, v0.y, v1.x, v1.y, v2.x, v2.y};

    // phi = (pi/2)*tanh(x); v_sin/v_cos take REVOLUTIONS: |t/4| <= 0.25
    float C[NQ], S[NQ];
#pragma unroll
    for (int i = 0; i < NQ; i++) {
        const float e = __builtin_amdgcn_exp2f(2.885390081777927f * xi[i]); // e^{2x}
        const float t = 1.0f - 2.0f * __builtin_amdgcn_rcpf(e + 1.0f);      // tanh(x)
        S[i] = __builtin_amdgcn_sinf(0.25f * t);
        C[i] = __builtin_amdgcn_cosf(0.25f * t);
    }

    // packed state: Rr[m]/Ri[m] hold slots (c<<4)|m for c = 0,1
    v2f Rr[16], Ri[16];

    // ---- layer 0 on |0>: product-state cascade (round-4/6-validated algebra) ----
    {
        const float4 m0 = M[0];
        GCOEF(m0, C[0], S[0], g00r, g00i, g01r, g01i)
        const float t0r = h0 ? g00r : -g01r;   // q0 row by lane parity
        const float t0i = h0 ? g00i : g01i;
        const float4 m1 = M[1];
        GCOEF(m1, C[1], S[1], h00r, h00i, h01r, h01i)
        // comp0 = t0 * g00(q1); comp1 = t0 * (-conj g01(q1))
        Rr[0] = (v2f){t0r * h00r - t0i * h00i, -(t0r * h01r + t0i * h01i)};
        Ri[0] = (v2f){t0r * h00i + t0i * h00r, t0r * h01i - t0i * h01r};
    }
#pragma unroll
    for (int q = 2; q < 6; q++) {
        const float4 mq = M[q];
        GCOEF(mq, C[q], S[q], g00r, g00i, g01r, g01i)
        const float Ar = g00r, Ai = g00i;      // bit=0 factor (g00)
        const float Br = -g01r, Bi = g01i;     // bit=1 factor (-conj(g01))
        const int bit = 1 << (5 - q);          // m-bit: 8,4,2,1
#pragma unroll
        for (int m = 0; m < 16; m++) {
            if ((m & (2 * bit - 1)) == 0) {    // occupied set
                const v2f pr = Rr[m], pi = Ri[m];
                Rr[m | bit] = pr * Br - pi * Bi;
                Ri[m | bit] = pr * Bi + pi * Br;
                Rr[m] = pr * Ar - pi * Ai;
                Ri[m] = pr * Ai + pi * Ar;
            }
        }
    }

    DO_RING();        // after layer 0
    DENSE_LAYER(1);
    DO_RING();        // after layer 1
    DENSE_LAYER(2);   // layer 2's ring folded into signs below

    // ---- expvals: packed signed partials; comp1 sign (bit4) folded at end ----
    v2f A0 = (v2f)(0.f), A1 = (v2f)(0.f), A2 = (v2f)(0.f), A3 = (v2f)(0.f), A4 = (v2f)(0.f);
#pragma unroll
    for (int m = 0; m < 16; m++) {
        const v2f p2 = Rr[m] * Rr[m] + Ri[m] * Ri[m];
        A0 += (__builtin_popcount(m & 0xF) & 1) ? -p2 : p2;
        A1 += p2;
        A2 += (__builtin_popcount(m & 0x8) & 1) ? -p2 : p2;
        A3 += (__builtin_popcount(m & 0xC) & 1) ? -p2 : p2;
        A4 += (__builtin_popcount(m & 0xE) & 1) ? -p2 : p2;
    }
    const float F0 = A0.x - A0.y;   // qubit0 (mask 0x1F) & qubit5 slot-part (0x3F)
    const float F1 = A1.x - A1.y;   // qubit1 (0x30)
    const float F2 = A2.x - A2.y;   // qubit2 (0x38)
    const float F3 = A3.x - A3.y;   // qubit3 (0x3C)
    const float F4 = A4.x - A4.y;   // qubit4 (0x3E)
    const float d1 = h0 ? F1 : -F1;
    const float d2 = h0 ? F2 : -F2;
    const float d3 = h0 ? F3 : -F3;
    const float d4 = h0 ? F4 : -F4;
    const float d5 = h0 ? F0 : -F0;
    float acc[NQ];
    acc[0] = F0 + __shfl_xor(F0, 1, 64);
    acc[1] = d1 + __shfl_xor(d1, 1, 64);
    acc[2] = d2 + __shfl_xor(d2, 1, 64);
    acc[3] = d3 + __shfl_xor(d3, 1, 64);
    acc[4] = d4 + __shfl_xor(d4, 1, 64);
    acc[5] = d5 + __shfl_xor(d5, 1, 64);

    const int off = b * 6 + (h0 ? 0 : 3);
    out[off + 0] = acc[h0 ? 0 : 3];
    out[off + 1] = acc[h0 ? 1 : 4];
    out[off + 2] = acc[h0 ? 2 : 5];
}

extern "C" void kernel_launch(void* const* d_in, const int* in_sizes, int n_in,
                              void* d_out, int out_size, void* d_ws, size_t ws_size,
                              hipStream_t stream) {
    const float* x = (const float*)d_in[0];
    const float* w = (const float*)d_in[1];
    float* out = (float*)d_out;
    float4* M = (float4*)d_ws;  // 18 * 16 B
    const int B = in_sizes[0] / NQ;
    gate_prep<<<1, 64, 0, stream>>>(w, M);
    const int threads = 2 * B;
    const int block = 256;
    const int grid = (threads + block - 1) / block;
    qsim_kernel<<<grid, block, 0, stream>>>(x, M, out, B);
}

// Round 14
// 92.718 us; speedup vs baseline: 1.6281x; 1.0794x over previous
//
#include <hip/hip_runtime.h>
#include <math.h>

#define NQ 6
#define NL 3

typedef float v2f __attribute__((ext_vector_type(2)));

// ---------- CNOT-ring permutation (bench-validated rounds 2-11) ----------
constexpr int cnot_map(int k, int ctrl, int tgt) {
    const int cb = 1 << (5 - ctrl), tb = 1 << (5 - tgt);
    return (k & cb) ? (k ^ tb) : k;
}
constexpr int ring_map(int k) {
    k = cnot_map(k, 5, 0);
    k = cnot_map(k, 4, 5);
    k = cnot_map(k, 3, 4);
    k = cnot_map(k, 2, 3);
    k = cnot_map(k, 1, 2);
    k = cnot_map(k, 0, 1);
    return k;
}
constexpr int ringN(int k, int n) {
    for (int i = 0; i < n; i++) k = ring_map(k);
    return k;
}
constexpr int inv_ringN(int p, int n) {
    for (int k = 0; k < 64; k++) if (ringN(k, n) == p) return k;
    return -1;
}
// Gate on logical qubit q with l rings skipped: physical pair mask Δ
constexpr int DELTA(int l, int q) { return ringN(1 << (5 - q), l); }
// Side mask σ: parity(σ & p) == logical bit (5-q) of physical p
constexpr int SIGMA(int l, int q) {
    int m = 0;
    for (int i = 0; i < 6; i++)
        if ((inv_ringN(1 << i, l) >> (5 - q)) & 1) m |= 1 << i;
    return m;
}
// Exhaustive verification vs validated ring_map: pairing linearity, side
// indicator for every physical index, and σ·Δ = 1 (pair straddles the gate).
constexpr bool check_conj() {
    int fwd[4][64] = {}, inv[4][64] = {};
    for (int k = 0; k < 64; k++) fwd[0][k] = k;
    for (int l = 1; l <= 3; l++)
        for (int k = 0; k < 64; k++) fwd[l][k] = ring_map(fwd[l - 1][k]);
    for (int l = 0; l <= 3; l++)
        for (int k = 0; k < 64; k++) inv[l][fwd[l][k]] = k;
    for (int l = 0; l <= 3; l++)
        for (int q = 0; q < 6; q++) {
            const int sg = SIGMA(l, q), dl = DELTA(l, q);
            for (int p = 0; p < 64; p++)
                if ((__builtin_popcount(sg & p) & 1) != ((inv[l][p] >> (5 - q)) & 1))
                    return false;
            if ((__builtin_popcount(sg & dl) & 1) != 1) return false;
            for (int k = 0; k < 64; k++)
                if (fwd[l][k ^ (1 << (5 - q))] != (fwd[l][k] ^ dl)) return false;
        }
    return true;
}
static_assert(check_conj(), "ring-conjugation masks mismatch vs validated ring_map");

// ---- prep kernel: M = RZ(a2)@RY(a1)@RZ(a0), SU(2) form (m00, m01) ----
__global__ void gate_prep(const float* __restrict__ w, float4* __restrict__ M) {
    const int g = threadIdx.x;
    if (g >= NL * NQ) return;
    const float a0 = w[g * 3 + 0], a1 = w[g * 3 + 1], a2 = w[g * 3 + 2];
    const float ch = cosf(0.5f * a1), sh = sinf(0.5f * a1);
    const float cp = cosf(0.5f * (a0 + a2)), sp = sinf(0.5f * (a0 + a2));
    const float cm = cosf(0.5f * (a0 - a2)), sm = sinf(0.5f * (a0 - a2));
    M[g] = make_float4(ch * cp, -ch * sp, -sh * cm, -sh * sm);
}

// G = M @ RY(c,s): g00 = m00*c + m01*s ; g01 = -m00*s + m01*c  (SU(2))
#define GCOEF(mq, c, s, g00r, g00i, g01r, g01i)                         \
    const float g00r = (mq).x * (c) + (mq).z * (s);                     \
    const float g00i = (mq).y * (c) + (mq).w * (s);                     \
    const float g01r = (mq).z * (c) - (mq).x * (s);                     \
    const float g01i = (mq).w * (c) - (mq).y * (s);

// Element coefficients by side s: A_0=g00, A_1=conj g00 (same real part);
// B_0=g01, B_1=-conj g01 (same imag part). Per-element:
//   new_r = e_r*g00r - e_i*KAi + p_r*KBr - p_i*g01i
//   new_i = e_i*g00r + e_r*KAi + p_i*KBr + p_r*g01i
// KAi(side) = side ? -g00i : g00i ; KBr(side) = side ? -g01r : g01r.
// Layout: physical index p = 2m + c (vector m = bits5..1, comp c = bit0).
// Pairing: m <-> m ^ vm. CANONICAL SELECTOR = one bit of vm (cvm); round-13
// bug was `!(m & vm)` which skips pairs when vm has >1 bit.
// L and Q MUST be integer literals (constexpr contexts inside).
#define APPLY_GATE(L, Q) do {                                               \
    constexpr int dlt = DELTA(L, Q);                                        \
    constexpr int sgm = SIGMA(L, Q);                                        \
    constexpr int vm  = dlt >> 1;                                           \
    constexpr int cf  = dlt & 1;                                            \
    constexpr int tt  = sgm & 1;                                            \
    constexpr int cvm = vm & (-vm);   /* single canonical bit of vm */      \
    asm volatile("" ::: "memory"); /* keep M load just-in-time */           \
    const float4 mq = M[(L) * NQ + (Q)];                                    \
    GCOEF(mq, C[Q], S[Q], g00r, g00i, g01r, g01i)                           \
    if constexpr (cf == 0) {                                                \
        /* partner keeps comp */                                            \
        _Pragma("unroll")                                                   \
        for (int m = 0; m < 32; m++) if (!(m & cvm)) {                      \
            const int m2 = m ^ vm;                                          \
            const int s0 = __builtin_popcount(sgm & (2 * m)) & 1;           \
            const v2f KAi = (v2f){ s0 ? -g00i : g00i, (s0^tt) ? -g00i : g00i }; \
            const v2f KBr = (v2f){ s0 ? -g01r : g01r, (s0^tt) ? -g01r : g01r }; \
            const v2f R0 = Rr[m], I0 = Ri[m], R1 = Rr[m2], I1 = Ri[m2];     \
            Rr[m]  = R0 * g00r - I0 * KAi + R1 * KBr - I1 * g01i;           \
            Ri[m]  = I0 * g00r + R0 * KAi + I1 * KBr + R1 * g01i;           \
            Rr[m2] = R1 * g00r + I1 * KAi - R0 * KBr - I0 * g01i;           \
            Ri[m2] = I1 * g00r - R1 * KAi - I0 * KBr + R0 * g01i;           \
        }                                                                   \
    } else if constexpr (vm == 0) {                                         \
        /* pure comp-flip: partner = own .yx */                             \
        _Pragma("unroll")                                                   \
        for (int m = 0; m < 32; m++) {                                      \
            const int s0 = __builtin_popcount(sgm & (2 * m)) & 1;           \
            const v2f KAi = (v2f){ s0 ? -g00i : g00i, (s0^tt) ? -g00i : g00i }; \
            const v2f KBr = (v2f){ s0 ? -g01r : g01r, (s0^tt) ? -g01r : g01r }; \
            const v2f R0 = Rr[m], I0 = Ri[m];                               \
            const v2f R0s = (v2f){R0.y, R0.x}, I0s = (v2f){I0.y, I0.x};     \
            Rr[m] = R0 * g00r - I0 * KAi + R0s * KBr - I0s * g01i;          \
            Ri[m] = I0 * g00r + R0 * KAi + I0s * KBr + R0s * g01i;          \
        }                                                                   \
    } else {                                                                \
        /* cross-vector + comp-flip: partner = other vector .yx */          \
        _Pragma("unroll")                                                   \
        for (int m = 0; m < 32; m++) if (!(m & cvm)) {                      \
            const int m2 = m ^ vm;                                          \
            const int s0 = __builtin_popcount(sgm & (2 * m)) & 1;           \
            const v2f KAi  = (v2f){ s0 ? -g00i : g00i, (s0^tt) ? -g00i : g00i };    \
            const v2f KBr  = (v2f){ s0 ? -g01r : g01r, (s0^tt) ? -g01r : g01r };    \
            const v2f KAi2 = (v2f){ (s0^1^tt) ? -g00i : g00i, (s0^1) ? -g00i : g00i }; \
            const v2f KBr2 = (v2f){ (s0^1^tt) ? -g01r : g01r, (s0^1) ? -g01r : g01r }; \
            const v2f R0 = Rr[m], I0 = Ri[m], R1 = Rr[m2], I1 = Ri[m2];     \
            const v2f R1s = (v2f){R1.y, R1.x}, I1s = (v2f){I1.y, I1.x};     \
            const v2f R0s = (v2f){R0.y, R0.x}, I0s = (v2f){I0.y, I0.x};     \
            Rr[m]  = R0 * g00r - I0 * KAi  + R1s * KBr  - I1s * g01i;       \
            Ri[m]  = I0 * g00r + R0 * KAi  + I1s * KBr  + R1s * g01i;       \
            Rr[m2] = R1 * g00r - I1 * KAi2 + R0s * KBr2 - I0s * g01i;       \
            Ri[m2] = I1 * g00r + R1 * KAi2 + I0s * KBr2 + R0s * g01i;       \
        }                                                                   \
    }                                                                       \
} while (0)

__global__ __launch_bounds__(256)
void qsim_kernel(const float* __restrict__ x, const float4* __restrict__ M,
                 float* __restrict__ out, int B) {
    const int b = blockIdx.x * blockDim.x + threadIdx.x;
    if (b >= B) return;

    const float2* x2 = (const float2*)x;
    const float2 v0 = x2[b * 3 + 0];
    const float2 v1 = x2[b * 3 + 1];
    const float2 v2 = x2[b * 3 + 2];
    const float xi[NQ] = {v0.x, v0.y, v1.x, v1.y, v2.x, v2.y};

    // phi = (pi/2)*tanh(x); v_sin/v_cos take REVOLUTIONS: |t/4| <= 0.25
    float C[NQ], S[NQ];
#pragma unroll
    for (int i = 0; i < NQ; i++) {
        const float e = __builtin_amdgcn_exp2f(2.885390081777927f * xi[i]); // e^{2x}
        const float t = 1.0f - 2.0f * __builtin_amdgcn_rcpf(e + 1.0f);      // tanh(x)
        S[i] = __builtin_amdgcn_sinf(0.25f * t);
        C[i] = __builtin_amdgcn_cosf(0.25f * t);
    }

    // Full 64-amp state per thread, packed: Rr[m]/Ri[m] comps = amps 2m, 2m+1
    v2f Rr[32], Ri[32];

    // ---- layer 0 on |0>: product-state cascade, scalar until q5 ----
    float ar0[32], ai0[32];
    {
        const float4 m0 = M[0];
        GCOEF(m0, C[0], S[0], g00r, g00i, g01r, g01i)
        ar0[0]  = g00r;  ai0[0]  = g00i;    // amp 0  (m=0)
        ar0[16] = -g01r; ai0[16] = g01i;    // amp 32 (m=16): -conj(g01)
    }
#pragma unroll
    for (int q = 1; q < 5; q++) {
        const float4 mq = M[q];
        GCOEF(mq, C[q], S[q], g00r, g00i, g01r, g01i)
        const float Ar = g00r, Ai = g00i;     // bit=0 factor
        const float Br = -g01r, Bi = g01i;    // bit=1 factor (-conj g01)
        const int mb = 16 >> q;
#pragma unroll
        for (int m = 0; m < 32; m++) {
            if ((m & ((32 >> q) - 1)) == 0) {  // occupied set
                const float pr = ar0[m], pi = ai0[m];
                ar0[m | mb] = pr * Br - pi * Bi;
                ai0[m | mb] = pr * Bi + pi * Br;
                ar0[m] = pr * Ar - pi * Ai;
                ai0[m] = pr * Ai + pi * Ar;
            }
        }
    }
    {   // q5: expand comps (amp bit0), building whole v2f
        const float4 mq = M[5];
        GCOEF(mq, C[5], S[5], g00r, g00i, g01r, g01i)
        const v2f KA1 = (v2f){g00r, -g01r};   // (A_r, B_r)
        const v2f KA2 = (v2f){g00i,  g01i};   // (A_i, B_i)
#pragma unroll
        for (int m = 0; m < 32; m++) {
            const float pr = ar0[m], pi = ai0[m];
            Rr[m] = pr * KA1 - pi * KA2;
            Ri[m] = pr * KA2 + pi * KA1;
        }
    }

    // ---- layers 1,2: ring-conjugated gates (zero ring instructions) ----
    APPLY_GATE(1, 0);
    APPLY_GATE(1, 1);
    APPLY_GATE(1, 2);
    APPLY_GATE(1, 3);
    APPLY_GATE(1, 4);
    APPLY_GATE(1, 5);
    APPLY_GATE(2, 0);
    APPLY_GATE(2, 1);
    APPLY_GATE(2, 2);
    APPLY_GATE(2, 3);
    APPLY_GATE(2, 4);
    APPLY_GATE(2, 5);

    // ---- expvals: 3rd ring folded into sign masks SIGMA(3,q) ----
    v2f A0 = (v2f)(0.f), A1 = (v2f)(0.f), A2 = (v2f)(0.f),
        A3 = (v2f)(0.f), A4 = (v2f)(0.f), A5 = (v2f)(0.f);
#pragma unroll
    for (int m = 0; m < 32; m++) {
        const v2f p2 = Rr[m] * Rr[m] + Ri[m] * Ri[m];
        A0 += (__builtin_popcount((SIGMA(3,0) >> 1) & m) & 1) ? -p2 : p2;
        A1 += (__builtin_popcount((SIGMA(3,1) >> 1) & m) & 1) ? -p2 : p2;
        A2 += (__builtin_popcount((SIGMA(3,2) >> 1) & m) & 1) ? -p2 : p2;
        A3 += (__builtin_popcount((SIGMA(3,3) >> 1) & m) & 1) ? -p2 : p2;
        A4 += (__builtin_popcount((SIGMA(3,4) >> 1) & m) & 1) ? -p2 : p2;
        A5 += (__builtin_popcount((SIGMA(3,5) >> 1) & m) & 1) ? -p2 : p2;
    }
    const float F0 = (SIGMA(3,0) & 1) ? (A0.x - A0.y) : (A0.x + A0.y);
    const float F1 = (SIGMA(3,1) & 1) ? (A1.x - A1.y) : (A1.x + A1.y);
    const float F2 = (SIGMA(3,2) & 1) ? (A2.x - A2.y) : (A2.x + A2.y);
    const float F3 = (SIGMA(3,3) & 1) ? (A3.x - A3.y) : (A3.x + A3.y);
    const float F4 = (SIGMA(3,4) & 1) ? (A4.x - A4.y) : (A4.x + A4.y);
    const float F5 = (SIGMA(3,5) & 1) ? (A5.x - A5.y) : (A5.x + A5.y);

    float2* o2 = (float2*)out;
    o2[b * 3 + 0] = make_float2(F0, F1);
    o2[b * 3 + 1] = make_float2(F2, F3);
    o2[b * 3 + 2] = make_float2(F4, F5);
}

extern "C" void kernel_launch(void* const* d_in, const int* in_sizes, int n_in,
                              void* d_out, int out_size, void* d_ws, size_t ws_size,
                              hipStream_t stream) {
    const float* x = (const float*)d_in[0];
    const float* w = (const float*)d_in[1];
    float* out = (float*)d_out;
    float4* M = (float4*)d_ws;  // 18 * 16 B
    const int B = in_sizes[0] / NQ;
    gate_prep<<<1, 64, 0, stream>>>(w, M);
    const int block = 256;
    const int grid = (B + block - 1) / block;
    qsim_kernel<<<grid, block, 0, stream>>>(x, M, out, B);
}

// Round 15
// 92.549 us; speedup vs baseline: 1.6311x; 1.0018x over previous
//
#include <hip/hip_runtime.h>
#include <math.h>

#define NQ 6
#define NL 3

typedef float v2f __attribute__((ext_vector_type(2)));

// ---------- CNOT-ring permutation (bench-validated rounds 2-14) ----------
constexpr int cnot_map(int k, int ctrl, int tgt) {
    const int cb = 1 << (5 - ctrl), tb = 1 << (5 - tgt);
    return (k & cb) ? (k ^ tb) : k;
}
constexpr int ring_map(int k) {
    k = cnot_map(k, 5, 0);
    k = cnot_map(k, 4, 5);
    k = cnot_map(k, 3, 4);
    k = cnot_map(k, 2, 3);
    k = cnot_map(k, 1, 2);
    k = cnot_map(k, 0, 1);
    return k;
}
constexpr int ringN(int k, int n) {
    for (int i = 0; i < n; i++) k = ring_map(k);
    return k;
}
constexpr int inv_ringN(int p, int n) {
    for (int k = 0; k < 64; k++) if (ringN(k, n) == p) return k;
    return -1;
}
// Gate on logical qubit q with l rings skipped: physical pair mask Δ
constexpr int DELTA(int l, int q) { return ringN(1 << (5 - q), l); }
// Side mask σ: parity(σ & p) == logical bit (5-q) of physical p
constexpr int SIGMA(int l, int q) {
    int m = 0;
    for (int i = 0; i < 6; i++)
        if ((inv_ringN(1 << i, l) >> (5 - q)) & 1) m |= 1 << i;
    return m;
}
// Exhaustive verification vs validated ring_map: pairing linearity, side
// indicator for every physical index, and σ·Δ = 1 (pair straddles the gate).
constexpr bool check_conj() {
    int fwd[4][64] = {}, inv[4][64] = {};
    for (int k = 0; k < 64; k++) fwd[0][k] = k;
    for (int l = 1; l <= 3; l++)
        for (int k = 0; k < 64; k++) fwd[l][k] = ring_map(fwd[l - 1][k]);
    for (int l = 0; l <= 3; l++)
        for (int k = 0; k < 64; k++) inv[l][fwd[l][k]] = k;
    for (int l = 0; l <= 3; l++)
        for (int q = 0; q < 6; q++) {
            const int sg = SIGMA(l, q), dl = DELTA(l, q);
            for (int p = 0; p < 64; p++)
                if ((__builtin_popcount(sg & p) & 1) != ((inv[l][p] >> (5 - q)) & 1))
                    return false;
            if ((__builtin_popcount(sg & dl) & 1) != 1) return false;
            for (int k = 0; k < 64; k++)
                if (fwd[l][k ^ (1 << (5 - q))] != (fwd[l][k] ^ dl)) return false;
        }
    return true;
}
static_assert(check_conj(), "ring-conjugation masks mismatch vs validated ring_map");

// ---- prep kernel: M = RZ(a2)@RY(a1)@RZ(a0), SU(2) form (m00, m01) ----
__global__ void gate_prep(const float* __restrict__ w, float4* __restrict__ M) {
    const int g = threadIdx.x;
    if (g >= NL * NQ) return;
    const float a0 = w[g * 3 + 0], a1 = w[g * 3 + 1], a2 = w[g * 3 + 2];
    const float ch = cosf(0.5f * a1), sh = sinf(0.5f * a1);
    const float cp = cosf(0.5f * (a0 + a2)), sp = sinf(0.5f * (a0 + a2));
    const float cm = cosf(0.5f * (a0 - a2)), sm = sinf(0.5f * (a0 - a2));
    M[g] = make_float4(ch * cp, -ch * sp, -sh * cm, -sh * sm);
}

// G = M @ RY(c,s): g00 = m00*c + m01*s ; g01 = -m00*s + m01*c  (SU(2))
#define GCOEF(mq, c, s, g00r, g00i, g01r, g01i)                         \
    const float g00r = (mq).x * (c) + (mq).z * (s);                     \
    const float g00i = (mq).y * (c) + (mq).w * (s);                     \
    const float g01r = (mq).z * (c) - (mq).x * (s);                     \
    const float g01i = (mq).w * (c) - (mq).y * (s);

// Element coefficients by side s: A_0=g00, A_1=conj g00 (same real part);
// B_0=g01, B_1=-conj g01 (same imag part). Per-element:
//   new_r = e_r*g00r - e_i*KAi + p_r*KBr - p_i*g01i
//   new_i = e_i*g00r + e_r*KAi + p_i*KBr + p_r*g01i
// KAi(side) = side ? -g00i : g00i ; KBr(side) = side ? -g01r : g01r.
// Layout: physical index p = 2m + c (vector m = bits5..1, comp c = bit0).
// Pairing: m <-> m ^ vm; canonical selector = one bit of vm (round-14 fix).
// NOTE (round 15): NO memory-clobber barrier — M loads are wave-uniform and
// the compiler hoists them to upfront s_load_dwordx4; the round-14 barriers
// created 12 serialized waitcnt stalls per thread (43 µs @ 31% issue eff).
#define APPLY_GATE(L, Q) do {                                               \
    constexpr int dlt = DELTA(L, Q);                                        \
    constexpr int sgm = SIGMA(L, Q);                                        \
    constexpr int vm  = dlt >> 1;                                           \
    constexpr int cf  = dlt & 1;                                            \
    constexpr int tt  = sgm & 1;                                            \
    constexpr int cvm = vm & (-vm);   /* single canonical bit of vm */      \
    const float4 mq = M[(L) * NQ + (Q)];                                    \
    GCOEF(mq, C[Q], S[Q], g00r, g00i, g01r, g01i)                           \
    if constexpr (cf == 0) {                                                \
        /* partner keeps comp */                                            \
        _Pragma("unroll")                                                   \
        for (int m = 0; m < 32; m++) if (!(m & cvm)) {                      \
            const int m2 = m ^ vm;                                          \
            const int s0 = __builtin_popcount(sgm & (2 * m)) & 1;           \
            const v2f KAi = (v2f){ s0 ? -g00i : g00i, (s0^tt) ? -g00i : g00i }; \
            const v2f KBr = (v2f){ s0 ? -g01r : g01r, (s0^tt) ? -g01r : g01r }; \
            const v2f R0 = Rr[m], I0 = Ri[m], R1 = Rr[m2], I1 = Ri[m2];     \
            Rr[m]  = R0 * g00r - I0 * KAi + R1 * KBr - I1 * g01i;           \
            Ri[m]  = I0 * g00r + R0 * KAi + I1 * KBr + R1 * g01i;           \
            Rr[m2] = R1 * g00r + I1 * KAi - R0 * KBr - I0 * g01i;           \
            Ri[m2] = I1 * g00r - R1 * KAi - I0 * KBr + R0 * g01i;           \
        }                                                                   \
    } else if constexpr (vm == 0) {                                         \
        /* pure comp-flip: partner = own .yx */                             \
        _Pragma("unroll")                                                   \
        for (int m = 0; m < 32; m++) {                                      \
            const int s0 = __builtin_popcount(sgm & (2 * m)) & 1;           \
            const v2f KAi = (v2f){ s0 ? -g00i : g00i, (s0^tt) ? -g00i : g00i }; \
            const v2f KBr = (v2f){ s0 ? -g01r : g01r, (s0^tt) ? -g01r : g01r }; \
            const v2f R0 = Rr[m], I0 = Ri[m];                               \
            const v2f R0s = (v2f){R0.y, R0.x}, I0s = (v2f){I0.y, I0.x};     \
            Rr[m] = R0 * g00r - I0 * KAi + R0s * KBr - I0s * g01i;          \
            Ri[m] = I0 * g00r + R0 * KAi + I0s * KBr + R0s * g01i;          \
        }                                                                   \
    } else {                                                                \
        /* cross-vector + comp-flip: partner = other vector .yx */          \
        _Pragma("unroll")                                                   \
        for (int m = 0; m < 32; m++) if (!(m & cvm)) {                      \
            const int m2 = m ^ vm;                                          \
            const int s0 = __builtin_popcount(sgm & (2 * m)) & 1;           \
            const v2f KAi  = (v2f){ s0 ? -g00i : g00i, (s0^tt) ? -g00i : g00i };    \
            const v2f KBr  = (v2f){ s0 ? -g01r : g01r, (s0^tt) ? -g01r : g01r };    \
            const v2f KAi2 = (v2f){ (s0^1^tt) ? -g00i : g00i, (s0^1) ? -g00i : g00i }; \
            const v2f KBr2 = (v2f){ (s0^1^tt) ? -g01r : g01r, (s0^1) ? -g01r : g01r }; \
            const v2f R0 = Rr[m], I0 = Ri[m], R1 = Rr[m2], I1 = Ri[m2];     \
            const v2f R1s = (v2f){R1.y, R1.x}, I1s = (v2f){I1.y, I1.x};     \
            const v2f R0s = (v2f){R0.y, R0.x}, I0s = (v2f){I0.y, I0.x};     \
            Rr[m]  = R0 * g00r - I0 * KAi  + R1s * KBr  - I1s * g01i;       \
            Ri[m]  = I0 * g00r + R0 * KAi  + I1s * KBr  + R1s * g01i;       \
            Rr[m2] = R1 * g00r - I1 * KAi2 + R0s * KBr2 - I0s * g01i;       \
            Ri[m2] = I1 * g00r + R1 * KAi2 + I0s * KBr2 + R0s * g01i;       \
        }                                                                   \
    }                                                                       \
} while (0)

__global__ __launch_bounds__(256)
void qsim_kernel(const float* __restrict__ x, const float4* __restrict__ M,
                 float* __restrict__ out, int B) {
    const int b = blockIdx.x * blockDim.x + threadIdx.x;
    if (b >= B) return;

    const float2* x2 = (const float2*)x;
    const float2 v0 = x2[b * 3 + 0];
    const float2 v1 = x2[b * 3 + 1];
    const float2 v2 = x2[b * 3 + 2];
    const float xi[NQ] = {v0.x, v0.y, v1.x, v1.y, v2.x, v2.y};

    // phi = (pi/2)*tanh(x); v_sin/v_cos take REVOLUTIONS: |t/4| <= 0.25
    float C[NQ], S[NQ];
#pragma unroll
    for (int i = 0; i < NQ; i++) {
        const float e = __builtin_amdgcn_exp2f(2.885390081777927f * xi[i]); // e^{2x}
        const float t = 1.0f - 2.0f * __builtin_amdgcn_rcpf(e + 1.0f);      // tanh(x)
        S[i] = __builtin_amdgcn_sinf(0.25f * t);
        C[i] = __builtin_amdgcn_cosf(0.25f * t);
    }

    // Full 64-amp state per thread, packed: Rr[m]/Ri[m] comps = amps 2m, 2m+1
    v2f Rr[32], Ri[32];

    // ---- layer 0 on |0>: product-state cascade, scalar until q5 ----
    float ar0[32], ai0[32];
    {
        const float4 m0 = M[0];
        GCOEF(m0, C[0], S[0], g00r, g00i, g01r, g01i)
        ar0[0]  = g00r;  ai0[0]  = g00i;    // amp 0  (m=0)
        ar0[16] = -g01r; ai0[16] = g01i;    // amp 32 (m=16): -conj(g01)
    }
#pragma unroll
    for (int q = 1; q < 5; q++) {
        const float4 mq = M[q];
        GCOEF(mq, C[q], S[q], g00r, g00i, g01r, g01i)
        const float Ar = g00r, Ai = g00i;     // bit=0 factor
        const float Br = -g01r, Bi = g01i;    // bit=1 factor (-conj g01)
        const int mb = 16 >> q;
#pragma unroll
        for (int m = 0; m < 32; m++) {
            if ((m & ((32 >> q) - 1)) == 0) {  // occupied set
                const float pr = ar0[m], pi = ai0[m];
                ar0[m | mb] = pr * Br - pi * Bi;
                ai0[m | mb] = pr * Bi + pi * Br;
                ar0[m] = pr * Ar - pi * Ai;
                ai0[m] = pr * Ai + pi * Ar;
            }
        }
    }
    {   // q5: expand comps (amp bit0), building whole v2f
        const float4 mq = M[5];
        GCOEF(mq, C[5], S[5], g00r, g00i, g01r, g01i)
        const v2f KA1 = (v2f){g00r, -g01r};   // (A_r, B_r)
        const v2f KA2 = (v2f){g00i,  g01i};   // (A_i, B_i)
#pragma unroll
        for (int m = 0; m < 32; m++) {
            const float pr = ar0[m], pi = ai0[m];
            Rr[m] = pr * KA1 - pi * KA2;
            Ri[m] = pr * KA2 + pi * KA1;
        }
    }

    // ---- layers 1,2: ring-conjugated gates (zero ring instructions) ----
    APPLY_GATE(1, 0);
    APPLY_GATE(1, 1);
    APPLY_GATE(1, 2);
    APPLY_GATE(1, 3);
    APPLY_GATE(1, 4);
    APPLY_GATE(1, 5);
    APPLY_GATE(2, 0);
    APPLY_GATE(2, 1);
    APPLY_GATE(2, 2);
    APPLY_GATE(2, 3);
    APPLY_GATE(2, 4);
    APPLY_GATE(2, 5);

    // ---- expvals: 3rd ring folded into sign masks SIGMA(3,q) ----
    v2f A0 = (v2f)(0.f), A1 = (v2f)(0.f), A2 = (v2f)(0.f),
        A3 = (v2f)(0.f), A4 = (v2f)(0.f), A5 = (v2f)(0.f);
#pragma unroll
    for (int m = 0; m < 32; m++) {
        const v2f p2 = Rr[m] * Rr[m] + Ri[m] * Ri[m];
        A0 += (__builtin_popcount((SIGMA(3,0) >> 1) & m) & 1) ? -p2 : p2;
        A1 += (__builtin_popcount((SIGMA(3,1) >> 1) & m) & 1) ? -p2 : p2;
        A2 += (__builtin_popcount((SIGMA(3,2) >> 1) & m) & 1) ? -p2 : p2;
        A3 += (__builtin_popcount((SIGMA(3,3) >> 1) & m) & 1) ? -p2 : p2;
        A4 += (__builtin_popcount((SIGMA(3,4) >> 1) & m) & 1) ? -p2 : p2;
        A5 += (__builtin_popcount((SIGMA(3,5) >> 1) & m) & 1) ? -p2 : p2;
    }
    const float F0 = (SIGMA(3,0) & 1) ? (A0.x - A0.y) : (A0.x + A0.y);
    const float F1 = (SIGMA(3,1) & 1) ? (A1.x - A1.y) : (A1.x + A1.y);
    const float F2 = (SIGMA(3,2) & 1) ? (A2.x - A2.y) : (A2.x + A2.y);
    const float F3 = (SIGMA(3,3) & 1) ? (A3.x - A3.y) : (A3.x + A3.y);
    const float F4 = (SIGMA(3,4) & 1) ? (A4.x - A4.y) : (A4.x + A4.y);
    const float F5 = (SIGMA(3,5) & 1) ? (A5.x - A5.y) : (A5.x + A5.y);

    float2* o2 = (float2*)out;
    o2[b * 3 + 0] = make_float2(F0, F1);
    o2[b * 3 + 1] = make_float2(F2, F3);
    o2[b * 3 + 2] = make_float2(F4, F5);
}

extern "C" void kernel_launch(void* const* d_in, const int* in_sizes, int n_in,
                              void* d_out, int out_size, void* d_ws, size_t ws_size,
                              hipStream_t stream) {
    const float* x = (const float*)d_in[0];
    const float* w = (const float*)d_in[1];
    float* out = (float*)d_out;
    float4* M = (float4*)d_ws;  // 18 * 16 B
    const int B = in_sizes[0] / NQ;
    gate_prep<<<1, 64, 0, stream>>>(w, M);
    const int block = 256;
    const int grid = (B + block - 1) / block;
    qsim_kernel<<<grid, block, 0, stream>>>(x, M, out, B);
}